// Round 1
// baseline (68.730 us; speedup 1.0000x reference)
//
#include <hip/hip_runtime.h>
#include <math.h>

// Problem constants (match reference)
#define B_TOTAL 32768
#define LBL 16
#define NS 1024

// Kernel geometry
#define SEGS 8                         // waves per block, each owns NS/SEGS states
#define B_PER_BLOCK 64                 // batch rows per block (= lanes per wave)
#define STATES_PER_SEG (NS / SEGS)     // 128
#define BLOCK_THREADS (SEGS * B_PER_BLOCK)  // 512
#define GRID_BLOCKS (B_TOTAL / B_PER_BLOCK) // 512

#if !__has_builtin(__builtin_amdgcn_exp2f)
static __device__ inline float __builtin_amdgcn_exp2f(float x) { return exp2f(x); }
#endif

__global__ __launch_bounds__(BLOCK_THREADS) void plm_main(
    const float* __restrict__ f, const float* __restrict__ y,
    const int* __restrict__ S, float* __restrict__ out,
    float* __restrict__ block_loss)
{
    __shared__ unsigned smask[NS];                       // 4 KB
    __shared__ float part[SEGS][B_PER_BLOCK][LBL + 1];   // 34.8 KB (z at [16]); stride 17 (odd) -> bank-conflict-free

    const int tid = threadIdx.x;

    // ---- Pack S ([NS][16] int32, 0/1) into 16-bit masks in LDS ----
    for (int s = tid; s < NS; s += BLOCK_THREADS) {
        const int* row = S + s * LBL;
        unsigned m = 0;
#pragma unroll
        for (int l = 0; l < LBL; ++l) m |= (row[l] > 0 ? 1u : 0u) << l;
        smask[s] = m;
    }
    __syncthreads();

    const int seg = tid >> 6;     // wave index 0..7 (wave-uniform)
    const int bl  = tid & 63;     // batch row within block
    const int b   = blockIdx.x * B_PER_BLOCK + bl;

    // ---- Load f row, pre-scale by log2(e) so v_exp_f32 (2^x) applies directly ----
    float f2[LBL];
    const float LOG2E = 1.4426950408889634f;
    const float4* frow = (const float4*)(f + (size_t)b * LBL);  // 64B-aligned
#pragma unroll
    for (int q = 0; q < 4; ++q) {
        float4 v = frow[q];
        f2[q * 4 + 0] = v.x * LOG2E;
        f2[q * 4 + 1] = v.y * LOG2E;
        f2[q * 4 + 2] = v.z * LOG2E;
        f2[q * 4 + 3] = v.w * LOG2E;
    }
    // Upper bound on any state's potential (in log2 units): sum of positive parts.
    // Guarantees exp2 arg <= 0 -> no overflow; underflow >= 2^-40 -> harmless in ratio.
    float U2 = 0.f;
#pragma unroll
    for (int l = 0; l < LBL; ++l) U2 += fmaxf(f2[l], 0.f);

    float z = 0.f;
    float num[LBL];
#pragma unroll
    for (int l = 0; l < LBL; ++l) num[l] = 0.f;

    // ---- Main loop: this wave's 128 states for this lane's batch row ----
    const int s0 = seg * STATES_PER_SEG;
#pragma unroll 2
    for (int i = 0; i < STATES_PER_SEG; ++i) {
        // mask is wave-uniform: force to SGPR so bit-selects stay on the SALU
        unsigned m = __builtin_amdgcn_readfirstlane(smask[s0 + i]);

        // dot(bits, f2) with 4 partial accumulators to break the FMA dep chain
        float pa = 0.f, pb = 0.f, pc = 0.f, pd = 0.f;
#pragma unroll
        for (int l = 0; l < LBL; l += 4) {
            float b0 = ((m >> (l + 0)) & 1u) ? 1.0f : 0.0f;
            float b1 = ((m >> (l + 1)) & 1u) ? 1.0f : 0.0f;
            float b2 = ((m >> (l + 2)) & 1u) ? 1.0f : 0.0f;
            float b3 = ((m >> (l + 3)) & 1u) ? 1.0f : 0.0f;
            pa = fmaf(b0, f2[l + 0], pa);
            pb = fmaf(b1, f2[l + 1], pb);
            pc = fmaf(b2, f2[l + 2], pc);
            pd = fmaf(b3, f2[l + 3], pd);
        }
        float p2 = (pa + pb) + (pc + pd);

        float e = __builtin_amdgcn_exp2f(p2 - U2);
        z += e;
#pragma unroll
        for (int l = 0; l < LBL; ++l) {
            float bf = ((m >> l) & 1u) ? 1.0f : 0.0f;
            num[l] = fmaf(bf, e, num[l]);
        }
    }

    // ---- Stash per-(seg,row) partials; shared shift U2 means merge is a plain sum ----
#pragma unroll
    for (int l = 0; l < LBL; ++l) part[seg][bl][l] = num[l];
    part[seg][bl][LBL] = z;
    __syncthreads();

    // ---- Epilogue: wave 0 merges segments, writes pMargin, computes loss ----
    float loss_part = 0.f;
    if (tid < B_PER_BLOCK) {
        const int blb = tid;
        const int bg  = blockIdx.x * B_PER_BLOCK + blb;

        float zt = 0.f;
        float nt[LBL];
#pragma unroll
        for (int l = 0; l < LBL; ++l) nt[l] = 0.f;
#pragma unroll
        for (int s = 0; s < SEGS; ++s) {
            zt += part[s][blb][LBL];
#pragma unroll
            for (int l = 0; l < LBL; ++l) nt[l] += part[s][blb][l];
        }

        const float inv_z = 1.0f / zt;
        const float* yrow = y + (size_t)bg * LBL;
        float* prow = out + 1 + (size_t)bg * LBL;

        float ls = 0.f;
#pragma unroll
        for (int l = 0; l < LBL; ++l) {
            float p = nt[l] * inv_z;
            prow[l] = p;
            float g = yrow[l];
            float fid = sqrtf(fmaf(p, g, 1e-8f)) +
                        sqrtf(fmaf(1.f - p, 1.f - g, 1e-8f));
            float pt = fmaf(p, g, (1.f - p) * (1.f - g));
            float at = fmaf(0.75f, g, 0.25f * (1.f - g));
            float om = 1.f - pt;
            ls += (1.f - fid) * at * om * om;
        }
        loss_part = ls;
    }
    if (tid < 64) {
#pragma unroll
        for (int off = 32; off; off >>= 1)
            loss_part += __shfl_down(loss_part, off);
        if (tid == 0) block_loss[blockIdx.x] = loss_part;
    }
}

__global__ __launch_bounds__(256) void plm_reduce(
    const float* __restrict__ block_loss, int n, float* __restrict__ out)
{
    __shared__ float wsum[4];
    float s = 0.f;
    for (int i = threadIdx.x; i < n; i += 256) s += block_loss[i];
#pragma unroll
    for (int off = 32; off; off >>= 1) s += __shfl_down(s, off);
    const int wave = threadIdx.x >> 6;
    if ((threadIdx.x & 63) == 0) wsum[wave] = s;
    __syncthreads();
    if (threadIdx.x == 0) {
        float t = wsum[0] + wsum[1] + wsum[2] + wsum[3];
        out[0] = t * (1.0f / ((float)B_TOTAL * (float)LBL));
    }
}

extern "C" void kernel_launch(void* const* d_in, const int* in_sizes, int n_in,
                              void* d_out, int out_size, void* d_ws, size_t ws_size,
                              hipStream_t stream) {
    const float* f = (const float*)d_in[0];   // [B, 16]
    const float* y = (const float*)d_in[1];   // [B, 16]
    const int*   S = (const int*)d_in[2];     // [1024, 16]
    float* out = (float*)d_out;               // [0]=loss, [1..]=pMargin
    float* bl  = (float*)d_ws;                // 512 block partials

    plm_main<<<GRID_BLOCKS, BLOCK_THREADS, 0, stream>>>(f, y, S, out, bl);
    plm_reduce<<<1, 256, 0, stream>>>(bl, GRID_BLOCKS, out);
}

// Round 2
// 26.114 us; speedup vs baseline: 2.6319x; 2.6319x over previous
//
#include <hip/hip_runtime.h>
#include <math.h>

#define B_TOTAL 32768
#define LBL 16
#define NSTATES 1024
#define BLOCK_THREADS 256          // 4 waves
#define B_PER_BLOCK 64             // 4 waves * 16 batch cols
#define GRID_BLOCKS (B_TOTAL / B_PER_BLOCK)  // 512

typedef __attribute__((ext_vector_type(8))) short bf16x8;
typedef __attribute__((ext_vector_type(4))) float f32x4;

#define LOG2E 1.4426950408889634f

static __device__ __forceinline__ unsigned short bf16_rne(float x) {
    union { float f; unsigned u; } v; v.f = x;
    unsigned r = v.u + 0x7FFFu + ((v.u >> 16) & 1u);
    return (unsigned short)(r >> 16);
}
static __device__ __forceinline__ float bf16_to_f(unsigned short h) {
    union { unsigned u; float f; } v; v.u = ((unsigned)h) << 16;
    return v.f;
}

__global__ __launch_bounds__(BLOCK_THREADS, 2) void plm_mfma(
    const float* __restrict__ f, const float* __restrict__ y,
    const int* __restrict__ S, float* __restrict__ out,
    float* __restrict__ block_loss)
{
    // LDS: 4096 + 33024 + 5120 + 5120 + 16 = ~47.4 KB -> 2 blocks/CU fits easily
    __shared__ __align__(16) unsigned smask[NSTATES];            // packed state masks
    __shared__ __align__(16) unsigned short Scm[LBL * 1032];     // S^T as bf16, padded row 2064B
    __shared__ __align__(16) unsigned LUT[256 * 5];              // byte -> 8 bf16 bits (20B stride)
    __shared__ __align__(16) unsigned P32[4][320];               // per-wave P tile [c*20 + pair]
    __shared__ float wls[4];

    const int tid = threadIdx.x;

    // ---- Prologue 1: pack masks + build S^T bf16 (column-major, padded) ----
    for (int s = tid; s < NSTATES; s += BLOCK_THREADS) {
        const int4* sp = (const int4*)(S + (size_t)s * LBL);
        int4 ra = sp[0], rb = sp[1], rc = sp[2], rd = sp[3];
        unsigned m = (unsigned)ra.x | ((unsigned)ra.y << 1) | ((unsigned)ra.z << 2) | ((unsigned)ra.w << 3)
                   | ((unsigned)rb.x << 4) | ((unsigned)rb.y << 5) | ((unsigned)rb.z << 6) | ((unsigned)rb.w << 7)
                   | ((unsigned)rc.x << 8) | ((unsigned)rc.y << 9) | ((unsigned)rc.z << 10) | ((unsigned)rc.w << 11)
                   | ((unsigned)rd.x << 12) | ((unsigned)rd.y << 13) | ((unsigned)rd.z << 14) | ((unsigned)rd.w << 15);
        smask[s] = m;
#pragma unroll
        for (int l = 0; l < LBL; ++l)
            Scm[l * 1032 + s] = (unsigned short)(((m >> l) & 1u) ? 0x3F80u : 0u);
    }
    // ---- Prologue 2: byte -> 8 bf16 expansion LUT (one entry per thread) ----
    {
        unsigned bt = (unsigned)tid;  // 256 threads == 256 bytes
        unsigned d0 = ((bt & 1u) ? 0x3F80u : 0u) | ((bt & 2u) ? 0x3F800000u : 0u);
        unsigned d1 = ((bt & 4u) ? 0x3F80u : 0u) | ((bt & 8u) ? 0x3F800000u : 0u);
        unsigned d2 = ((bt & 16u) ? 0x3F80u : 0u) | ((bt & 32u) ? 0x3F800000u : 0u);
        unsigned d3 = ((bt & 64u) ? 0x3F80u : 0u) | ((bt & 128u) ? 0x3F800000u : 0u);
        LUT[bt * 5 + 0] = d0; LUT[bt * 5 + 1] = d1;
        LUT[bt * 5 + 2] = d2; LUT[bt * 5 + 3] = d3;
    }
    __syncthreads();

    // ---- Per-wave setup ----
    const int w = tid >> 6;
    const int lane = tid & 63;
    const int c = lane & 15;        // batch col (B operands) / row index (A operands)
    const int g = lane >> 4;        // lane group 0..3
    const int b = blockIdx.x * B_PER_BLOCK + w * LBL + c;
    const int h = g & 1;            // which 8-label half this lane's k-range covers
    const int hilo = g >> 1;        // 0: bf16-hi of f, 1: residual-lo
    const int msh = 8 * h;

    // load this lane's 8 labels of f
    const float4* fr = (const float4*)(f + (size_t)b * LBL + h * 8);
    float4 x0 = fr[0], x1 = fr[1];
    float xs[8] = { x0.x, x0.y, x0.z, x0.w, x1.x, x1.y, x1.z, x1.w };

    // U = sum of positive parts of full row (shared shift; arg of exp2 <= ~0)
    float up = 0.f;
#pragma unroll
    for (int j = 0; j < 8; ++j) up += fmaxf(xs[j], 0.f);
    float U = up + __shfl_xor(up, 16);
    const float ebias = -U * LOG2E;

    // B1 fragment: k<16 -> bf16(f), k>=16 -> bf16(f - float(bf16(f)))
    union { unsigned short s[8]; bf16x8 v; } b1u;
#pragma unroll
    for (int j = 0; j < 8; ++j) {
        unsigned short hb = bf16_rne(xs[j]);
        unsigned short lb = bf16_rne(xs[j] - bf16_to_f(hb));
        b1u.s[j] = (unsigned short)(hilo ? lb : hb);
    }
    const bf16x8 b1f = b1u.v;

    unsigned* Pw = &P32[w][0];
    f32x4 cacc = 0.0f;
    float zacc = 0.f;

    // ---- Main loop: 32 iters x 32 states; no barriers (P is wave-private) ----
#pragma unroll 2
    for (int t2 = 0; t2 < 32; ++t2) {
#pragma unroll
        for (int q = 0; q < 2; ++q) {
            const int ct = t2 * 2 + q;
            unsigned mrow = smask[ct * 16 + c];            // state row = lane&15
            unsigned byt = (mrow >> msh) & 0xFFu;
            unsigned q0 = LUT[byt * 5 + 0], q1 = LUT[byt * 5 + 1];
            unsigned q2 = LUT[byt * 5 + 2], q3 = LUT[byt * 5 + 3];
            union { unsigned u[4]; bf16x8 v; } a1u;
            a1u.u[0] = q0; a1u.u[1] = q1; a1u.u[2] = q2; a1u.u[3] = q3;

            f32x4 zero4 = 0.0f;
            f32x4 pot = __builtin_amdgcn_mfma_f32_16x16x32_bf16(a1u.v, b1f, zero4, 0, 0, 0);

            float e0 = exp2f(fmaf(pot[0], LOG2E, ebias));
            float e1 = exp2f(fmaf(pot[1], LOG2E, ebias));
            float e2 = exp2f(fmaf(pot[2], LOG2E, ebias));
            float e3 = exp2f(fmaf(pot[3], LOG2E, ebias));
            zacc += (e0 + e1) + (e2 + e3);

            unsigned pk0 = (unsigned)bf16_rne(e0) | ((unsigned)bf16_rne(e1) << 16);
            unsigned pk1 = (unsigned)bf16_rne(e2) | ((unsigned)bf16_rne(e3) << 16);
            Pw[c * 20 + q * 8 + 2 * g]     = pk0;          // states q*16+4g, +1
            Pw[c * 20 + q * 8 + 2 * g + 1] = pk1;          // states q*16+4g+2, +3
        }
        // MFMA2: num[l][c] += S^T[l][k-states] * P[k-states][c], K=32
        bf16x8 a2 = *(const bf16x8*)&Scm[(unsigned)c * 1032 + t2 * 32 + 8 * g];
        bf16x8 b2 = *(const bf16x8*)&Pw[c * 20 + 4 * g];
        cacc = __builtin_amdgcn_mfma_f32_16x16x32_bf16(a2, b2, cacc, 0, 0, 0);
    }

    // ---- Epilogue ----
    float z = zacc + __shfl_xor(zacc, 16);
    z += __shfl_xor(z, 32);
    const float invz = 1.0f / z;

    const float4 yv = *(const float4*)(y + (size_t)b * LBL + 4 * g);
    float yr[4] = { yv.x, yv.y, yv.z, yv.w };

    float ls = 0.f;
    float* prow = out + 1 + (size_t)b * LBL + 4 * g;
#pragma unroll
    for (int r = 0; r < 4; ++r) {
        float p = cacc[r] * invz;
        prow[r] = p;
        float gv = yr[r];
        float fid = sqrtf(fmaf(p, gv, 1e-8f)) + sqrtf(fmaf(1.f - p, 1.f - gv, 1e-8f));
        float pt = fmaf(p, gv, (1.f - p) * (1.f - gv));
        float at = fmaf(0.75f, gv, 0.25f * (1.f - gv));
        float om = 1.f - pt;
        ls += (1.f - fid) * at * om * om;
    }
#pragma unroll
    for (int off = 32; off; off >>= 1) ls += __shfl_down(ls, off);
    if (lane == 0) wls[w] = ls;
    __syncthreads();
    if (tid == 0) block_loss[blockIdx.x] = (wls[0] + wls[1]) + (wls[2] + wls[3]);
}

__global__ __launch_bounds__(256) void plm_reduce(
    const float* __restrict__ block_loss, int n, float* __restrict__ out)
{
    __shared__ float wsum[4];
    float s = 0.f;
    for (int i = threadIdx.x; i < n; i += 256) s += block_loss[i];
#pragma unroll
    for (int off = 32; off; off >>= 1) s += __shfl_down(s, off);
    const int wave = threadIdx.x >> 6;
    if ((threadIdx.x & 63) == 0) wsum[wave] = s;
    __syncthreads();
    if (threadIdx.x == 0) {
        float t = (wsum[0] + wsum[1]) + (wsum[2] + wsum[3]);
        out[0] = t * (1.0f / ((float)B_TOTAL * (float)LBL));
    }
}

extern "C" void kernel_launch(void* const* d_in, const int* in_sizes, int n_in,
                              void* d_out, int out_size, void* d_ws, size_t ws_size,
                              hipStream_t stream) {
    const float* f = (const float*)d_in[0];   // [B, 16]
    const float* y = (const float*)d_in[1];   // [B, 16]
    const int*   S = (const int*)d_in[2];     // [1024, 16]
    float* out = (float*)d_out;               // [0]=loss, [1..]=pMargin
    float* bl  = (float*)d_ws;                // 512 block partials

    plm_mfma<<<GRID_BLOCKS, BLOCK_THREADS, 0, stream>>>(f, y, S, out, bl);
    plm_reduce<<<1, 256, 0, stream>>>(bl, GRID_BLOCKS, out);
}

// Round 3
// 23.238 us; speedup vs baseline: 2.9577x; 1.1238x over previous
//
#include <hip/hip_runtime.h>
#include <math.h>

#define LBL 16
#define NSTATES 1024
#define B_TOTAL 32768
#define WAVES 8
#define BLOCK_THREADS (WAVES * 64)              // 512
#define COLS_PER_BLOCK 64
#define GRID_BLOCKS (B_TOTAL / COLS_PER_BLOCK)  // 512
#define HALF_STATES 512
#define TILES 16                                // 512 states / 32 per tile

typedef __attribute__((ext_vector_type(8))) short bf16x8;
typedef __attribute__((ext_vector_type(4))) float f32x4;

#define LOG2E 1.4426950408889634f

#if __has_builtin(__builtin_amdgcn_exp2f)
#define EXP2F __builtin_amdgcn_exp2f
#else
#define EXP2F exp2f
#endif

static __device__ __forceinline__ unsigned short bf16_rne(float x) {
    union { float f; unsigned u; } v; v.f = x;
    unsigned r = v.u + 0x7FFFu + ((v.u >> 16) & 1u);
    return (unsigned short)(r >> 16);
}
static __device__ __forceinline__ float bf16_to_f(unsigned short h) {
    union { unsigned u; float f; } v; v.u = ((unsigned)h) << 16;
    return v.f;
}
static __device__ __forceinline__ unsigned cvt_pk_bf16(float lo, float hi) {
    unsigned r;
    asm("v_cvt_pk_bf16_f32 %0, %1, %2" : "=v"(r) : "v"(lo), "v"(hi));
    return r;
}

__global__ __launch_bounds__(BLOCK_THREADS, 4) void plm_mfma2(
    const float* __restrict__ f, const float* __restrict__ y,
    const int* __restrict__ S, float* __restrict__ out,
    float* __restrict__ block_loss)
{
    // LDS: 4096 + 33024 + 20480 + 10240 + 32 = ~67.9 KB -> 2 blocks/CU, 16 waves/CU = 4/SIMD
    __shared__ __align__(16) unsigned smask[NSTATES];          // packed state masks
    __shared__ __align__(16) unsigned short Scm[LBL * 1032];   // S^T bf16, padded stride (2064B)
    __shared__ __align__(16) unsigned Pbuf[WAVES][2][320];     // per-wave double-buffered P tile
    __shared__ __align__(16) float part[WAVES][16][20];        // [w][c][0..15]=num, [16+g]=z part
    __shared__ float wls[WAVES];

    const int tid = threadIdx.x;

    // ---- Prologue: pack masks + build S^T bf16 (column-major, padded) ----
    for (int s = tid; s < NSTATES; s += BLOCK_THREADS) {
        const int4* sp = (const int4*)(S + (size_t)s * LBL);
        int4 ra = sp[0], rb = sp[1], rc = sp[2], rd = sp[3];
        unsigned m = (unsigned)ra.x | ((unsigned)ra.y << 1) | ((unsigned)ra.z << 2) | ((unsigned)ra.w << 3)
                   | ((unsigned)rb.x << 4) | ((unsigned)rb.y << 5) | ((unsigned)rb.z << 6) | ((unsigned)rb.w << 7)
                   | ((unsigned)rc.x << 8) | ((unsigned)rc.y << 9) | ((unsigned)rc.z << 10) | ((unsigned)rc.w << 11)
                   | ((unsigned)rd.x << 12) | ((unsigned)rd.y << 13) | ((unsigned)rd.z << 14) | ((unsigned)rd.w << 15);
        smask[s] = m;
#pragma unroll
        for (int l = 0; l < LBL; ++l)
            Scm[l * 1032 + s] = (unsigned short)(((m >> l) & 1u) ? 0x3F80u : 0u);
    }
    __syncthreads();

    // ---- Per-wave setup ----
    const int w = tid >> 6;
    const int lane = tid & 63;
    const int c = lane & 15;          // batch col within group / MFMA row index
    const int g = lane >> 4;          // lane group 0..3
    const int cg = w & 3;             // column group
    const int sh = (w >> 2) * HALF_STATES;  // state half base
    const int b = blockIdx.x * COLS_PER_BLOCK + cg * LBL + c;
    const int h = g & 1;              // label half for this lane's k-range
    const int hilo = g >> 1;          // 0: bf16 hi of f, 1: residual lo
    const unsigned bsh = 8u * (unsigned)h;

    // load this lane's 8 labels of f
    const float4* fr = (const float4*)(f + (size_t)b * LBL + h * 8);
    float4 x0 = fr[0], x1 = fr[1];
    float xs[8] = { x0.x, x0.y, x0.z, x0.w, x1.x, x1.y, x1.z, x1.w };

    // U = sum of positive parts (shared shift; exp2 arg <= 0 always)
    float up = 0.f;
#pragma unroll
    for (int j = 0; j < 8; ++j) up += fmaxf(xs[j], 0.f);
    float U = up + __shfl_xor(up, 16);
    const float ebias = -U * LOG2E;

    // B1 fragment: k<16 -> bf16(f), k>=16 -> bf16 residual
    union { unsigned short s[8]; bf16x8 v; } b1u;
#pragma unroll
    for (int j = 0; j < 8; ++j) {
        unsigned short hb = bf16_rne(xs[j]);
        unsigned short lb = bf16_rne(xs[j] - bf16_to_f(hb));
        b1u.s[j] = (unsigned short)(hilo ? lb : hb);
    }
    const bf16x8 b1f = b1u.v;

    unsigned* P0 = &Pbuf[w][0][0];
    unsigned* P1 = &Pbuf[w][1][0];
    f32x4 cacc = 0.0f;
    float zacc = 0.f;

    // ---- produce: MFMA1 + exp + pack into P tile (wave-private, no barriers) ----
    auto produce = [&](int t, unsigned* Pcur) {
        const int sidx = sh + t * 32 + c;
        unsigned m0 = smask[sidx];        // chunk q=0 (compiler fuses into ds_read2_b32)
        unsigned m1 = smask[sidx + 16];   // chunk q=1
        unsigned mh0 = m0 >> bsh, mh1 = m1 >> bsh;

        union { unsigned u[4]; bf16x8 v; } a0, a1;
#pragma unroll
        for (int j = 0; j < 4; ++j) {
            unsigned t0 = mh0 >> (2 * j), t1 = mh1 >> (2 * j);
            a0.u[j] = (t0 & 1u) * 0x3F80u + (t0 & 2u) * 0x1FC00000u;
            a1.u[j] = (t1 & 1u) * 0x3F80u + (t1 & 2u) * 0x1FC00000u;
        }
        f32x4 zero4 = 0.0f;
        f32x4 pot0 = __builtin_amdgcn_mfma_f32_16x16x32_bf16(a0.v, b1f, zero4, 0, 0, 0);
        f32x4 pot1 = __builtin_amdgcn_mfma_f32_16x16x32_bf16(a1.v, b1f, zero4, 0, 0, 0);

        float e0 = EXP2F(fmaf(pot0[0], LOG2E, ebias));
        float e1 = EXP2F(fmaf(pot0[1], LOG2E, ebias));
        float e2 = EXP2F(fmaf(pot0[2], LOG2E, ebias));
        float e3 = EXP2F(fmaf(pot0[3], LOG2E, ebias));
        float e4 = EXP2F(fmaf(pot1[0], LOG2E, ebias));
        float e5 = EXP2F(fmaf(pot1[1], LOG2E, ebias));
        float e6 = EXP2F(fmaf(pot1[2], LOG2E, ebias));
        float e7 = EXP2F(fmaf(pot1[3], LOG2E, ebias));
        zacc += ((e0 + e1) + (e2 + e3)) + ((e4 + e5) + (e6 + e7));

        uint2 pkA, pkB;
        pkA.x = cvt_pk_bf16(e0, e1); pkA.y = cvt_pk_bf16(e2, e3);
        pkB.x = cvt_pk_bf16(e4, e5); pkB.y = cvt_pk_bf16(e6, e7);
        *(uint2*)&Pcur[c * 20 + 2 * g]     = pkA;   // q=0: k-pairs 4g..4g+3
        *(uint2*)&Pcur[c * 20 + 8 + 2 * g] = pkB;   // q=1: k-pairs 16+4g..
    };
    // ---- consume: MFMA2 over a previously produced P tile ----
    auto consume = [&](int t, const unsigned* Pprev) {
        bf16x8 a2 = *(const bf16x8*)&Scm[(unsigned)c * 1032 + sh + t * 32 + 8 * g];
        bf16x8 b2 = *(const bf16x8*)&Pprev[c * 20 + 4 * g];
        cacc = __builtin_amdgcn_mfma_f32_16x16x32_bf16(a2, b2, cacc, 0, 0, 0);
    };

    // ---- Main loop, software-pipelined: consume(t-1) overlaps produce(t) ----
    produce(0, P0);
    for (int tp = 0; tp < 7; ++tp) {
        produce(2 * tp + 1, P1); consume(2 * tp,     P0);
        produce(2 * tp + 2, P0); consume(2 * tp + 1, P1);
    }
    produce(15, P1); consume(14, P0);
    consume(15, P1);

    // ---- Stash partials ----
    *(f32x4*)&part[w][c][4 * g] = cacc;
    part[w][c][16 + g] = zacc;
    __syncthreads();

    // ---- Final: merge halves, write pMargin, loss ----
    {
        const int cg2 = tid >> 7;          // 0..3
        const int c2  = (tid >> 3) & 15;   // 0..15
        const int lp  = tid & 7;           // label pair
        const int w0 = cg2, w1 = cg2 + 4;
        const int bg = blockIdx.x * COLS_PER_BLOCK + cg2 * LBL + c2;

        float z = 0.f;
#pragma unroll
        for (int gg = 0; gg < 4; ++gg)
            z += part[w0][c2][16 + gg] + part[w1][c2][16 + gg];
        const float invz = 1.0f / z;

        const float2 yv = *(const float2*)(y + (size_t)bg * LBL + 2 * lp);
        float yr[2] = { yv.x, yv.y };
        float* prow = out + 1 + (size_t)bg * LBL + 2 * lp;

        float ls = 0.f;
#pragma unroll
        for (int r = 0; r < 2; ++r) {
            const int l = 2 * lp + r;
            float num = part[w0][c2][l] + part[w1][c2][l];
            float p = num * invz;
            prow[r] = p;
            float gv = yr[r];
            float fid = sqrtf(fmaf(p, gv, 1e-8f)) + sqrtf(fmaf(1.f - p, 1.f - gv, 1e-8f));
            float pt = fmaf(p, gv, (1.f - p) * (1.f - gv));
            float at = fmaf(0.75f, gv, 0.25f * (1.f - gv));
            float om = 1.f - pt;
            ls += (1.f - fid) * at * om * om;
        }
#pragma unroll
        for (int off = 32; off; off >>= 1) ls += __shfl_down(ls, off);
        if (lane == 0) wls[w] = ls;
    }
    __syncthreads();
    if (tid == 0) {
        float t = 0.f;
#pragma unroll
        for (int i = 0; i < WAVES; ++i) t += wls[i];
        block_loss[blockIdx.x] = t;
    }
}

__global__ __launch_bounds__(256) void plm_reduce(
    const float* __restrict__ block_loss, int n, float* __restrict__ out)
{
    __shared__ float wsum[4];
    float s = 0.f;
    for (int i = threadIdx.x; i < n; i += 256) s += block_loss[i];
#pragma unroll
    for (int off = 32; off; off >>= 1) s += __shfl_down(s, off);
    const int wave = threadIdx.x >> 6;
    if ((threadIdx.x & 63) == 0) wsum[wave] = s;
    __syncthreads();
    if (threadIdx.x == 0) {
        float t = (wsum[0] + wsum[1]) + (wsum[2] + wsum[3]);
        out[0] = t * (1.0f / ((float)B_TOTAL * (float)LBL));
    }
}

extern "C" void kernel_launch(void* const* d_in, const int* in_sizes, int n_in,
                              void* d_out, int out_size, void* d_ws, size_t ws_size,
                              hipStream_t stream) {
    const float* f = (const float*)d_in[0];   // [B, 16]
    const float* y = (const float*)d_in[1];   // [B, 16]
    const int*   S = (const int*)d_in[2];     // [1024, 16]
    float* out = (float*)d_out;               // [0]=loss, [1..]=pMargin
    float* bl  = (float*)d_ws;                // 512 block partials

    plm_mfma2<<<GRID_BLOCKS, BLOCK_THREADS, 0, stream>>>(f, y, S, out, bl);
    plm_reduce<<<1, 256, 0, stream>>>(bl, GRID_BLOCKS, out);
}